// Round 1
// baseline (953.873 us; speedup 1.0000x reference)
//
#include <hip/hip_runtime.h>
#include <hip/hip_bf16.h>
#include <stdint.h>

// ---------------- problem constants ----------------
constexpr int NN = 100000;     // nodes
constexpr int NE = 1600000;    // edges
constexpr int NG = 64;         // graphs
constexpr int S  = 192;        // row stride (elements) for all node-feature buffers
constexpr int NB_SCAN = 98;    // ceil(100000/1024)

typedef __bf16 bf16x8 __attribute__((ext_vector_type(8)));
typedef float  f32x16 __attribute__((ext_vector_type(16)));

union U16x4 { uint4 u; bf16x8 b; };

// bf16(stored as ushort/uint halves) <-> f32 helpers
__device__ __forceinline__ float bl(unsigned int u) { return __uint_as_float(u << 16); }
__device__ __forceinline__ float bh(unsigned int u) { return __uint_as_float(u & 0xffff0000u); }
__device__ __forceinline__ unsigned int fb(float f) {  // f32 -> bf16 bits, RTNE
    unsigned int u = __float_as_uint(f);
    return (u + 0x7fffu + ((u >> 16) & 1u)) >> 16;
}

// ---------------- preprocessing kernels ----------------
__global__ __launch_bounds__(256) void k_indeg(const int* __restrict__ ei, int* __restrict__ indeg) {
    int e = blockIdx.x * 256 + threadIdx.x;
    if (e < NE) atomicAdd(&indeg[ei[NE + e]], 1);
}

__global__ __launch_bounds__(1024) void k_scan1(const int* __restrict__ indeg, int* __restrict__ offs,
                                                int* __restrict__ partials) {
    __shared__ int s[1024];
    int t = threadIdx.x;
    int gid = blockIdx.x * 1024 + t;
    int v = (gid < NN) ? indeg[gid] : 0;
    s[t] = v;
    __syncthreads();
    for (int d = 1; d < 1024; d <<= 1) {
        int tv = (t >= d) ? s[t - d] : 0;
        __syncthreads();
        s[t] += tv;
        __syncthreads();
    }
    if (gid < NN) offs[gid + 1] = s[t];
    if (t == 1023) partials[blockIdx.x] = s[1023];
}

__global__ void k_scan2(int* __restrict__ offs, int* __restrict__ partials) {
    if (threadIdx.x == 0 && blockIdx.x == 0) {
        offs[0] = 0;
        int run = 0;
        for (int b = 0; b < NB_SCAN; b++) { int tv = partials[b]; partials[b] = run; run += tv; }
    }
}

__global__ __launch_bounds__(1024) void k_scan3(int* __restrict__ offs, const int* __restrict__ partials) {
    int gid = blockIdx.x * 1024 + threadIdx.x;
    if (gid < NN) offs[gid + 1] += partials[blockIdx.x];
}

__global__ __launch_bounds__(256) void k_csr(const int* __restrict__ ei, const int* __restrict__ offs,
                                             int* __restrict__ cursor, int* __restrict__ csr) {
    int e = blockIdx.x * 256 + threadIdx.x;
    if (e < NE) {
        int sn = ei[e];
        int d  = ei[NE + e];
        int pos = offs[d] + atomicAdd(&cursor[d], 1);
        csr[pos] = sn;
    }
}

// x f32 [NN,128] -> A bf16 (stride 192) and R = relu bf16
__global__ __launch_bounds__(256) void k_convx(const float* __restrict__ x, unsigned short* __restrict__ A_,
                                               unsigned short* __restrict__ R_) {
    int id = blockIdx.x * 256 + threadIdx.x;   // one float4 each; total NN*128/4
    if (id >= NN * 32) return;
    int row = id >> 5;
    int c4  = id & 31;
    float4 v = ((const float4*)x)[id];
    int base = row * S + c4 * 4;
    uint2 a, r;
    a.x = fb(v.x) | (fb(v.y) << 16);
    a.y = fb(v.z) | (fb(v.w) << 16);
    r.x = fb(fmaxf(v.x, 0.f)) | (fb(fmaxf(v.y, 0.f)) << 16);
    r.y = fb(fmaxf(v.z, 0.f)) | (fb(fmaxf(v.w, 0.f)) << 16);
    *(uint2*)(A_ + base) = a;
    *(uint2*)(R_ + base) = r;
}

// W f32 [K,N] -> chunk-major bf16: WtC[(k/8)*N + n][j] = W[(k/8)*8+j, n]
__global__ __launch_bounds__(256) void k_convw(const float* __restrict__ W, unsigned short* __restrict__ WtC,
                                               int K, int N, int total) {
    int id = blockIdx.x * 256 + threadIdx.x;
    if (id >= total) return;
    int ci = id >> 3, j = id & 7;
    int kc = ci / N, n = ci % N;
    WtC[id] = (unsigned short)fb(W[(kc * 8 + j) * N + n]);
}

// ---------------- aggregation: y[i] = x[i] + eps*deg + sum_{e in CSR[i]} r[src_e] ----------------
// one wave per node; lane owns features [4*lane, 4*lane+4); IN-PLACE into A (gathers read R only)
template <int D>
__global__ __launch_bounds__(256) void k_agg(unsigned short* A_, const unsigned short* __restrict__ R_,
                                             const int* __restrict__ offs, const int* __restrict__ indeg,
                                             const int* __restrict__ csr) {
    const int w = threadIdx.x >> 6, lane = threadIdx.x & 63;
    const int i = blockIdx.x * 4 + w;
    constexpr int Q = D / 4;
    const bool act = lane < Q;
    const int deg = indeg[i];
    const int start = offs[i];
    float a0 = 0.f, a1 = 0.f, a2 = 0.f, a3 = 0.f;
    unsigned short* arow = A_ + (size_t)i * S + lane * 4;
    if (act) {
        uint2 p = *(const uint2*)arow;
        a0 = bl(p.x); a1 = bh(p.x); a2 = bl(p.y); a3 = bh(p.y);
    }
    const float ed = 1e-7f * (float)deg;
    a0 += ed; a1 += ed; a2 += ed; a3 += ed;
    const char* rbase = (const char*)R_ + lane * 8;
    for (int e0 = 0; e0 < deg; e0 += 64) {
        int idx = e0 + lane;
        int eid = (idx < deg) ? csr[start + idx] : 0;
        int cnt = min(64, deg - e0);
        for (int j = 0; j < cnt; ++j) {
            int sn = __shfl(eid, j);
            if (act) {
                uint2 p = *(const uint2*)(rbase + sn * 384);
                a0 += bl(p.x); a1 += bh(p.x); a2 += bl(p.y); a3 += bh(p.y);
            }
        }
    }
    if (act) {
        uint2 o;
        o.x = fb(a0) | (fb(a1) << 16);
        o.y = fb(a2) | (fb(a3) << 16);
        *(uint2*)arow = o;
    }
}

// ---------------- GEMM: h = y @ W + b (in-place into A), R = relu(h) ----------------
// wave computes 32 rows x N cols; B chunk-major from global (L2-hot, <=74KB)
template <int K, int N, bool WR>
__global__ __launch_bounds__(256) void k_gemm(const unsigned short* Ain, const unsigned short* __restrict__ WtC,
                                              const float* __restrict__ bias, unsigned short* Aout,
                                              unsigned short* Rout) {
    static_assert(K % 16 == 0 && N % 32 == 0, "");
    const int w = threadIdx.x >> 6, lane = threadIdx.x & 63;
    const int rt = blockIdx.x * 4 + w;
    if (rt >= (NN / 32)) return;
    const int hl = lane >> 5, lr = lane & 31;
    const int row0 = rt * 32;
    f32x16 acc[N / 32];
#pragma unroll
    for (int c = 0; c < N / 32; c++)
#pragma unroll
        for (int r = 0; r < 16; r++) acc[c][r] = 0.f;

    const unsigned short* ap = Ain + (row0 + lr) * S + hl * 8;
    const uint4* b4 = (const uint4*)WtC;
#pragma unroll
    for (int ks = 0; ks < K / 16; ks++) {
        U16x4 a;
        a.u = *(const uint4*)(ap + ks * 16);
#pragma unroll
        for (int c = 0; c < N / 32; c++) {
            U16x4 b;
            b.u = b4[(ks * 2 + hl) * N + c * 32 + lr];
            acc[c] = __builtin_amdgcn_mfma_f32_32x32x16_bf16(a.b, b.b, acc[c], 0, 0, 0);
        }
    }
#pragma unroll
    for (int c = 0; c < N / 32; c++) {
        const int col = c * 32 + lr;
        const float bc = bias[col];
#pragma unroll
        for (int r = 0; r < 16; r++) {
            const int row = row0 + (r & 3) + 8 * (r >> 2) + 4 * hl;
            float v = acc[c][r] + bc;
            Aout[row * S + col] = (unsigned short)fb(v);
            if (WR) Rout[row * S + col] = (unsigned short)fb(fmaxf(v, 0.f));
        }
    }
}

// ---------------- pooling + head ----------------
__global__ __launch_bounds__(128) void k_pool(const unsigned short* __restrict__ A_, const int* __restrict__ batch,
                                              float* __restrict__ sums, float* __restrict__ cnt) {
    const int b = blockIdx.x;      // 500 blocks x 200 nodes
    const int f = threadIdx.x;     // 128 features
    int n0 = b * 200;
    int n1 = min(n0 + 200, NN);
    int cur = batch[n0];
    float acc = 0.f;
    int run = 0;
    for (int n = n0; n < n1; n++) {
        int g = batch[n];
        if (g != cur) {
            atomicAdd(&sums[cur * 128 + f], acc);
            if (f == 0) atomicAdd(&cnt[cur], (float)run);
            acc = 0.f; run = 0; cur = g;
        }
        acc += __uint_as_float(((unsigned int)A_[(size_t)n * S + f]) << 16);
        run++;
    }
    atomicAdd(&sums[cur * 128 + f], acc);
    if (f == 0) atomicAdd(&cnt[cur], (float)run);
}

__global__ __launch_bounds__(64) void k_head(const float* __restrict__ sums, const float* __restrict__ cnt,
                                             const float* __restrict__ Wfc, const float* __restrict__ bfc,
                                             float* __restrict__ out) {
    __shared__ float pooled[128];
    __shared__ float lg[10];
    const int g = blockIdx.x, t = threadIdx.x;
    float inv = 1.f / fmaxf(cnt[g], 1.f);
    pooled[t]      = sums[g * 128 + t] * inv;
    pooled[t + 64] = sums[g * 128 + t + 64] * inv;
    __syncthreads();
    if (t < 10) {
        float s = bfc[t];
        for (int f = 0; f < 128; f++) s += pooled[f] * Wfc[f * 10 + t];
        lg[t] = s;
    }
    __syncthreads();
    if (t < 10) {
        float m = lg[0];
        for (int k = 1; k < 10; k++) m = fmaxf(m, lg[k]);
        float se = 0.f;
        for (int k = 0; k < 10; k++) se += expf(lg[k] - m);
        out[g * 10 + t] = lg[t] - m - logf(se);
    }
}

// ---------------- workspace layout (bytes) ----------------
constexpr size_t A_OFF      = 0;                    // 38,400,000
constexpr size_t R_OFF      = 38400000;             // 38,400,000
constexpr size_t CSR_OFF    = 76800000;             // 6,400,000
constexpr size_t OFFS_OFF   = 83200000;             // 400,128 (100001 ints padded)
constexpr size_t INDEG_OFF  = 83600128;             // 400,000
constexpr size_t CURSOR_OFF = 84000128;             // 400,000
constexpr size_t PART_OFF   = 84400128;             // 512
constexpr size_t WT0_OFF    = 84400640;             // 49,152
constexpr size_t WT1_OFF    = 84449792;             // 73,728
constexpr size_t WT2_OFF    = 84523520;             // 73,728
constexpr size_t WT3_OFF    = 84597248;             // 49,152
constexpr size_t SUMS_OFF   = 84646400;             // 32,768
constexpr size_t CNT_OFF    = 84679168;             // 256

extern "C" void kernel_launch(void* const* d_in, const int* in_sizes, int n_in,
                              void* d_out, int out_size, void* d_ws, size_t ws_size,
                              hipStream_t stream) {
    const float* x   = (const float*)d_in[0];
    const float* W0  = (const float*)d_in[1];
    const float* b0  = (const float*)d_in[2];
    const float* W1  = (const float*)d_in[3];
    const float* b1  = (const float*)d_in[4];
    const float* W2  = (const float*)d_in[5];
    const float* b2  = (const float*)d_in[6];
    const float* W3  = (const float*)d_in[7];
    const float* b3  = (const float*)d_in[8];
    const float* Wfc = (const float*)d_in[9];
    const float* bfc = (const float*)d_in[10];
    const int*   ei  = (const int*)d_in[11];
    const int*   bat = (const int*)d_in[12];
    float* out = (float*)d_out;

    char* ws = (char*)d_ws;
    unsigned short* A_  = (unsigned short*)(ws + A_OFF);
    unsigned short* R_  = (unsigned short*)(ws + R_OFF);
    int* csr    = (int*)(ws + CSR_OFF);
    int* offs   = (int*)(ws + OFFS_OFF);
    int* indeg  = (int*)(ws + INDEG_OFF);
    int* cursor = (int*)(ws + CURSOR_OFF);
    int* part   = (int*)(ws + PART_OFF);
    unsigned short* Wt0 = (unsigned short*)(ws + WT0_OFF);
    unsigned short* Wt1 = (unsigned short*)(ws + WT1_OFF);
    unsigned short* Wt2 = (unsigned short*)(ws + WT2_OFF);
    unsigned short* Wt3 = (unsigned short*)(ws + WT3_OFF);
    float* sums = (float*)(ws + SUMS_OFF);
    float* cnt  = (float*)(ws + CNT_OFF);

    // zero indeg+cursor (contiguous) and pool sums+cnt (contiguous)
    hipMemsetAsync(ws + INDEG_OFF, 0, 800000, stream);
    hipMemsetAsync(ws + SUMS_OFF, 0, 33024, stream);

    // CSR build
    k_indeg<<<NE / 256, 256, 0, stream>>>(ei, indeg);
    k_scan1<<<NB_SCAN, 1024, 0, stream>>>(indeg, offs, part);
    k_scan2<<<1, 64, 0, stream>>>(offs, part);
    k_scan3<<<NB_SCAN, 1024, 0, stream>>>(offs, part);
    k_csr<<<NE / 256, 256, 0, stream>>>(ei, offs, cursor, csr);

    // input + weight conversion
    k_convx<<<NN * 32 / 256, 256, 0, stream>>>(x, A_, R_);
    k_convw<<<(128 * 192 + 255) / 256, 256, 0, stream>>>(W0, Wt0, 128, 192, 128 * 192);
    k_convw<<<(192 * 192 + 255) / 256, 256, 0, stream>>>(W1, Wt1, 192, 192, 192 * 192);
    k_convw<<<(192 * 192 + 255) / 256, 256, 0, stream>>>(W2, Wt2, 192, 192, 192 * 192);
    k_convw<<<(192 * 128 + 255) / 256, 256, 0, stream>>>(W3, Wt3, 192, 128, 192 * 128);

    const int AGG_GRID  = NN / 4;                   // 25000 blocks, 1 wave/node
    const int GEMM_GRID = (NN / 32 + 3) / 4;        // 782 blocks, 1 wave/32-row tile

    // layer 0: d=128 -> 192
    k_agg<128><<<AGG_GRID, 256, 0, stream>>>(A_, R_, offs, indeg, csr);
    k_gemm<128, 192, true><<<GEMM_GRID, 256, 0, stream>>>(A_, Wt0, b0, A_, R_);
    // layer 1: 192 -> 192
    k_agg<192><<<AGG_GRID, 256, 0, stream>>>(A_, R_, offs, indeg, csr);
    k_gemm<192, 192, true><<<GEMM_GRID, 256, 0, stream>>>(A_, Wt1, b1, A_, R_);
    // layer 2: 192 -> 192
    k_agg<192><<<AGG_GRID, 256, 0, stream>>>(A_, R_, offs, indeg, csr);
    k_gemm<192, 192, true><<<GEMM_GRID, 256, 0, stream>>>(A_, Wt2, b2, A_, R_);
    // layer 3: 192 -> 128 (no relu output needed)
    k_agg<192><<<AGG_GRID, 256, 0, stream>>>(A_, R_, offs, indeg, csr);
    k_gemm<192, 128, false><<<GEMM_GRID, 256, 0, stream>>>(A_, Wt3, b3, A_, R_);

    // pool + head
    k_pool<<<500, 128, 0, stream>>>(A_, bat, sums, cnt);
    k_head<<<NG, 64, 0, stream>>>(sums, cnt, Wfc, bfc, out);
}

// Round 2
// 805.580 us; speedup vs baseline: 1.1841x; 1.1841x over previous
//
#include <hip/hip_runtime.h>
#include <hip/hip_bf16.h>
#include <stdint.h>

// ---------------- problem constants ----------------
constexpr int NN = 100000;     // nodes
constexpr int NE = 1600000;    // edges
constexpr int NG = 64;         // graphs
constexpr int S  = 192;        // row stride (elements) for all node-feature buffers
constexpr int NB_SCAN = 98;    // ceil(100000/1024)
constexpr int CSR_PASSES = 4;  // dst-range passes for L2-resident scatter
constexpr int PASS_W = 25000;  // NN / CSR_PASSES

typedef __bf16 bf16x8 __attribute__((ext_vector_type(8)));
typedef float  f32x16 __attribute__((ext_vector_type(16)));

union U16x4 { uint4 u; bf16x8 b; };

// bf16(stored as ushort/uint halves) <-> f32 helpers
__device__ __forceinline__ float bl(unsigned int u) { return __uint_as_float(u << 16); }
__device__ __forceinline__ float bh(unsigned int u) { return __uint_as_float(u & 0xffff0000u); }
__device__ __forceinline__ unsigned int fb(float f) {  // f32 -> bf16 bits, RTNE
    unsigned int u = __float_as_uint(f);
    return (u + 0x7fffu + ((u >> 16) & 1u)) >> 16;
}

// ---------------- preprocessing kernels ----------------
__global__ __launch_bounds__(256) void k_indeg(const int* __restrict__ ei, int* __restrict__ indeg) {
    int e2 = (blockIdx.x * 256 + threadIdx.x) * 2;
    if (e2 < NE) {
        int2 d = *(const int2*)(ei + NE + e2);
        atomicAdd(&indeg[d.x], 1);
        atomicAdd(&indeg[d.y], 1);
    }
}

__global__ __launch_bounds__(1024) void k_scan1(const int* __restrict__ indeg, int* __restrict__ offs,
                                                int* __restrict__ partials) {
    __shared__ int s[1024];
    int t = threadIdx.x;
    int gid = blockIdx.x * 1024 + t;
    int v = (gid < NN) ? indeg[gid] : 0;
    s[t] = v;
    __syncthreads();
    for (int d = 1; d < 1024; d <<= 1) {
        int tv = (t >= d) ? s[t - d] : 0;
        __syncthreads();
        s[t] += tv;
        __syncthreads();
    }
    if (gid < NN) offs[gid + 1] = s[t];
    if (t == 1023) partials[blockIdx.x] = s[1023];
}

__global__ void k_scan2(int* __restrict__ offs, int* __restrict__ partials) {
    if (threadIdx.x == 0 && blockIdx.x == 0) {
        offs[0] = 0;
        int run = 0;
        for (int b = 0; b < NB_SCAN; b++) { int tv = partials[b]; partials[b] = run; run += tv; }
    }
}

__global__ __launch_bounds__(1024) void k_scan3(int* __restrict__ offs, const int* __restrict__ partials) {
    int gid = blockIdx.x * 1024 + threadIdx.x;
    if (gid < NN) offs[gid + 1] += partials[blockIdx.x];
}

// one dst-range pass of the CSR scatter: only dsts in [lo,hi) are filled.
// region written per pass (~1.6MB csr slice + 100KB cursor slice) stays L2-resident.
__global__ __launch_bounds__(256) void k_csr(const int* __restrict__ ei, const int* __restrict__ offs,
                                             int* __restrict__ cursor, int* __restrict__ csr,
                                             int lo, int hi) {
    int e2 = (blockIdx.x * 256 + threadIdx.x) * 2;
    if (e2 >= NE) return;
    int2 sv = *(const int2*)(ei + e2);
    int2 dv = *(const int2*)(ei + NE + e2);
    if (dv.x >= lo && dv.x < hi) {
        int pos = offs[dv.x] + atomicAdd(&cursor[dv.x], 1);
        csr[pos] = sv.x;
    }
    if (dv.y >= lo && dv.y < hi) {
        int pos = offs[dv.y] + atomicAdd(&cursor[dv.y], 1);
        csr[pos] = sv.y;
    }
}

// x f32 [NN,128] -> A bf16 (stride 192) and R = relu bf16
__global__ __launch_bounds__(256) void k_convx(const float* __restrict__ x, unsigned short* __restrict__ A_,
                                               unsigned short* __restrict__ R_) {
    int id = blockIdx.x * 256 + threadIdx.x;   // one float4 each; total NN*128/4
    if (id >= NN * 32) return;
    int row = id >> 5;
    int c4  = id & 31;
    float4 v = ((const float4*)x)[id];
    int base = row * S + c4 * 4;
    uint2 a, r;
    a.x = fb(v.x) | (fb(v.y) << 16);
    a.y = fb(v.z) | (fb(v.w) << 16);
    r.x = fb(fmaxf(v.x, 0.f)) | (fb(fmaxf(v.y, 0.f)) << 16);
    r.y = fb(fmaxf(v.z, 0.f)) | (fb(fmaxf(v.w, 0.f)) << 16);
    *(uint2*)(A_ + base) = a;
    *(uint2*)(R_ + base) = r;
}

// W f32 [K,N] -> chunk-major bf16: WtC[(k/8)*N + n][j] = W[(k/8)*8+j, n]
__global__ __launch_bounds__(256) void k_convw(const float* __restrict__ W, unsigned short* __restrict__ WtC,
                                               int K, int N, int total) {
    int id = blockIdx.x * 256 + threadIdx.x;
    if (id >= total) return;
    int ci = id >> 3, j = id & 7;
    int kc = ci / N, n = ci % N;
    WtC[id] = (unsigned short)fb(W[(kc * 8 + j) * N + n]);
}

// ---------------- aggregation: y[i] = x[i] + eps*deg + sum_{e in CSR[i]} r[src_e] ----------------
// one wave per node; lane owns features [4*lane, 4*lane+4); IN-PLACE into A (gathers read R only).
// 8 gather loads kept in flight per unrolled step to amortize L3 latency.
template <int D>
__global__ __launch_bounds__(256) void k_agg(unsigned short* A_, const unsigned short* __restrict__ R_,
                                             const int* __restrict__ offs, const int* __restrict__ indeg,
                                             const int* __restrict__ csr) {
    const int w = threadIdx.x >> 6, lane = threadIdx.x & 63;
    const int i = blockIdx.x * 4 + w;
    constexpr int Q = D / 4;
    const bool act = lane < Q;
    const int deg = indeg[i];
    const int start = offs[i];
    float a0 = 0.f, a1 = 0.f, a2 = 0.f, a3 = 0.f;
    unsigned short* arow = A_ + (size_t)i * S + lane * 4;
    if (act) {
        uint2 p = *(const uint2*)arow;
        a0 = bl(p.x); a1 = bh(p.x); a2 = bl(p.y); a3 = bh(p.y);
    }
    const float ed = 1e-7f * (float)deg;
    a0 += ed; a1 += ed; a2 += ed; a3 += ed;
    const char* rbase = (const char*)R_ + lane * 8;
    for (int e0 = 0; e0 < deg; e0 += 64) {
        int idx = e0 + lane;
        int eid = (idx < deg) ? csr[start + idx] : 0;   // lane's CSR entry (safe default)
        int cnt = min(64, deg - e0);
        for (int j = 0; j < cnt; j += 8) {
            int sn[8];
#pragma unroll
            for (int k = 0; k < 8; k++) sn[k] = __shfl(eid, (j + k) & 63);
            uint2 p[8];
#pragma unroll
            for (int k = 0; k < 8; k++) {
                p[k].x = 0u; p[k].y = 0u;
                if ((j + k < cnt) && act)    // (j+k<cnt) is wave-uniform; 8 loads batch-issue
                    p[k] = *(const uint2*)(rbase + (size_t)sn[k] * 384);
            }
#pragma unroll
            for (int k = 0; k < 8; k++) {
                a0 += bl(p[k].x); a1 += bh(p[k].x); a2 += bl(p[k].y); a3 += bh(p[k].y);
            }
        }
    }
    if (act) {
        uint2 o;
        o.x = fb(a0) | (fb(a1) << 16);
        o.y = fb(a2) | (fb(a3) << 16);
        *(uint2*)arow = o;
    }
}

// ---------------- GEMM: h = y @ W + b (in-place into A), R = relu(h) ----------------
// wave computes 32 rows x N cols; B chunk-major from global (L2-hot, <=74KB)
template <int K, int N, bool WR>
__global__ __launch_bounds__(256) void k_gemm(const unsigned short* Ain, const unsigned short* __restrict__ WtC,
                                              const float* __restrict__ bias, unsigned short* Aout,
                                              unsigned short* Rout) {
    static_assert(K % 16 == 0 && N % 32 == 0, "");
    const int w = threadIdx.x >> 6, lane = threadIdx.x & 63;
    const int rt = blockIdx.x * 4 + w;
    if (rt >= (NN / 32)) return;
    const int hl = lane >> 5, lr = lane & 31;
    const int row0 = rt * 32;
    f32x16 acc[N / 32];
#pragma unroll
    for (int c = 0; c < N / 32; c++)
#pragma unroll
        for (int r = 0; r < 16; r++) acc[c][r] = 0.f;

    const unsigned short* ap = Ain + (row0 + lr) * S + hl * 8;
    const uint4* b4 = (const uint4*)WtC;
#pragma unroll
    for (int ks = 0; ks < K / 16; ks++) {
        U16x4 a;
        a.u = *(const uint4*)(ap + ks * 16);
#pragma unroll
        for (int c = 0; c < N / 32; c++) {
            U16x4 b;
            b.u = b4[(ks * 2 + hl) * N + c * 32 + lr];
            acc[c] = __builtin_amdgcn_mfma_f32_32x32x16_bf16(a.b, b.b, acc[c], 0, 0, 0);
        }
    }
#pragma unroll
    for (int c = 0; c < N / 32; c++) {
        const int col = c * 32 + lr;
        const float bc = bias[col];
#pragma unroll
        for (int r = 0; r < 16; r++) {
            const int row = row0 + (r & 3) + 8 * (r >> 2) + 4 * hl;
            float v = acc[c][r] + bc;
            Aout[row * S + col] = (unsigned short)fb(v);
            if (WR) Rout[row * S + col] = (unsigned short)fb(fmaxf(v, 0.f));
        }
    }
}

// ---------------- pooling + head ----------------
__global__ __launch_bounds__(128) void k_pool(const unsigned short* __restrict__ A_, const int* __restrict__ batch,
                                              float* __restrict__ sums, float* __restrict__ cnt) {
    const int b = blockIdx.x;      // 500 blocks x 200 nodes
    const int f = threadIdx.x;     // 128 features
    int n0 = b * 200;
    int n1 = min(n0 + 200, NN);
    int cur = batch[n0];
    float acc = 0.f;
    int run = 0;
    for (int n = n0; n < n1; n++) {
        int g = batch[n];
        if (g != cur) {
            atomicAdd(&sums[cur * 128 + f], acc);
            if (f == 0) atomicAdd(&cnt[cur], (float)run);
            acc = 0.f; run = 0; cur = g;
        }
        acc += __uint_as_float(((unsigned int)A_[(size_t)n * S + f]) << 16);
        run++;
    }
    atomicAdd(&sums[cur * 128 + f], acc);
    if (f == 0) atomicAdd(&cnt[cur], (float)run);
}

__global__ __launch_bounds__(64) void k_head(const float* __restrict__ sums, const float* __restrict__ cnt,
                                             const float* __restrict__ Wfc, const float* __restrict__ bfc,
                                             float* __restrict__ out) {
    __shared__ float pooled[128];
    __shared__ float lg[10];
    const int g = blockIdx.x, t = threadIdx.x;
    float inv = 1.f / fmaxf(cnt[g], 1.f);
    pooled[t]      = sums[g * 128 + t] * inv;
    pooled[t + 64] = sums[g * 128 + t + 64] * inv;
    __syncthreads();
    if (t < 10) {
        float s = bfc[t];
        for (int f = 0; f < 128; f++) s += pooled[f] * Wfc[f * 10 + t];
        lg[t] = s;
    }
    __syncthreads();
    if (t < 10) {
        float m = lg[0];
        for (int k = 1; k < 10; k++) m = fmaxf(m, lg[k]);
        float se = 0.f;
        for (int k = 0; k < 10; k++) se += expf(lg[k] - m);
        out[g * 10 + t] = lg[t] - m - logf(se);
    }
}

// ---------------- workspace layout (bytes) ----------------
constexpr size_t A_OFF      = 0;                    // 38,400,000
constexpr size_t R_OFF      = 38400000;             // 38,400,000
constexpr size_t CSR_OFF    = 76800000;             // 6,400,000
constexpr size_t OFFS_OFF   = 83200000;             // 400,128 (100001 ints padded)
constexpr size_t INDEG_OFF  = 83600128;             // 400,000
constexpr size_t CURSOR_OFF = 84000128;             // 400,000
constexpr size_t PART_OFF   = 84400128;             // 512
constexpr size_t WT0_OFF    = 84400640;             // 49,152
constexpr size_t WT1_OFF    = 84449792;             // 73,728
constexpr size_t WT2_OFF    = 84523520;             // 73,728
constexpr size_t WT3_OFF    = 84597248;             // 49,152
constexpr size_t SUMS_OFF   = 84646400;             // 32,768
constexpr size_t CNT_OFF    = 84679168;             // 256

extern "C" void kernel_launch(void* const* d_in, const int* in_sizes, int n_in,
                              void* d_out, int out_size, void* d_ws, size_t ws_size,
                              hipStream_t stream) {
    const float* x   = (const float*)d_in[0];
    const float* W0  = (const float*)d_in[1];
    const float* b0  = (const float*)d_in[2];
    const float* W1  = (const float*)d_in[3];
    const float* b1  = (const float*)d_in[4];
    const float* W2  = (const float*)d_in[5];
    const float* b2  = (const float*)d_in[6];
    const float* W3  = (const float*)d_in[7];
    const float* b3  = (const float*)d_in[8];
    const float* Wfc = (const float*)d_in[9];
    const float* bfc = (const float*)d_in[10];
    const int*   ei  = (const int*)d_in[11];
    const int*   bat = (const int*)d_in[12];
    float* out = (float*)d_out;

    char* ws = (char*)d_ws;
    unsigned short* A_  = (unsigned short*)(ws + A_OFF);
    unsigned short* R_  = (unsigned short*)(ws + R_OFF);
    int* csr    = (int*)(ws + CSR_OFF);
    int* offs   = (int*)(ws + OFFS_OFF);
    int* indeg  = (int*)(ws + INDEG_OFF);
    int* cursor = (int*)(ws + CURSOR_OFF);
    int* part   = (int*)(ws + PART_OFF);
    unsigned short* Wt0 = (unsigned short*)(ws + WT0_OFF);
    unsigned short* Wt1 = (unsigned short*)(ws + WT1_OFF);
    unsigned short* Wt2 = (unsigned short*)(ws + WT2_OFF);
    unsigned short* Wt3 = (unsigned short*)(ws + WT3_OFF);
    float* sums = (float*)(ws + SUMS_OFF);
    float* cnt  = (float*)(ws + CNT_OFF);

    // zero indeg+cursor (contiguous) and pool sums+cnt (contiguous)
    hipMemsetAsync(ws + INDEG_OFF, 0, 800000, stream);
    hipMemsetAsync(ws + SUMS_OFF, 0, 33024, stream);

    // CSR build
    k_indeg<<<NE / 512, 256, 0, stream>>>(ei, indeg);
    k_scan1<<<NB_SCAN, 1024, 0, stream>>>(indeg, offs, part);
    k_scan2<<<1, 64, 0, stream>>>(offs, part);
    k_scan3<<<NB_SCAN, 1024, 0, stream>>>(offs, part);
    for (int p = 0; p < CSR_PASSES; p++)
        k_csr<<<NE / 512, 256, 0, stream>>>(ei, offs, cursor, csr, p * PASS_W, (p + 1) * PASS_W);

    // input + weight conversion
    k_convx<<<NN * 32 / 256, 256, 0, stream>>>(x, A_, R_);
    k_convw<<<(128 * 192 + 255) / 256, 256, 0, stream>>>(W0, Wt0, 128, 192, 128 * 192);
    k_convw<<<(192 * 192 + 255) / 256, 256, 0, stream>>>(W1, Wt1, 192, 192, 192 * 192);
    k_convw<<<(192 * 192 + 255) / 256, 256, 0, stream>>>(W2, Wt2, 192, 192, 192 * 192);
    k_convw<<<(192 * 128 + 255) / 256, 256, 0, stream>>>(W3, Wt3, 192, 128, 192 * 128);

    const int AGG_GRID  = NN / 4;                   // 25000 blocks, 1 wave/node
    const int GEMM_GRID = (NN / 32 + 3) / 4;        // 782 blocks, 1 wave/32-row tile

    // layer 0: d=128 -> 192
    k_agg<128><<<AGG_GRID, 256, 0, stream>>>(A_, R_, offs, indeg, csr);
    k_gemm<128, 192, true><<<GEMM_GRID, 256, 0, stream>>>(A_, Wt0, b0, A_, R_);
    // layer 1: 192 -> 192
    k_agg<192><<<AGG_GRID, 256, 0, stream>>>(A_, R_, offs, indeg, csr);
    k_gemm<192, 192, true><<<GEMM_GRID, 256, 0, stream>>>(A_, Wt1, b1, A_, R_);
    // layer 2: 192 -> 192
    k_agg<192><<<AGG_GRID, 256, 0, stream>>>(A_, R_, offs, indeg, csr);
    k_gemm<192, 192, true><<<GEMM_GRID, 256, 0, stream>>>(A_, Wt2, b2, A_, R_);
    // layer 3: 192 -> 128 (no relu output needed)
    k_agg<192><<<AGG_GRID, 256, 0, stream>>>(A_, R_, offs, indeg, csr);
    k_gemm<192, 128, false><<<GEMM_GRID, 256, 0, stream>>>(A_, Wt3, b3, A_, R_);

    // pool + head
    k_pool<<<500, 128, 0, stream>>>(A_, bat, sums, cnt);
    k_head<<<NG, 64, 0, stream>>>(sums, cnt, Wfc, bfc, out);
}